// Round 11
// baseline (457.968 us; speedup 1.0000x reference)
//
#include <hip/hip_runtime.h>
#include <hip/hip_fp16.h>

#define D 128
#define BIN_CH 8192
#define CAP 6144   // per-bucket edge capacity (mean 4081, sigma ~64 -> 32-sigma headroom)

typedef _Float16 f16x4 __attribute__((ext_vector_type(4)));
typedef float f32x4 __attribute__((ext_vector_type(4)));

// ---- k_init: block 0 = dtype-detect + bcur/dhist init; blocks 1..48 = W transpose ----
__global__ __launch_bounds__(256) void k_init(const int* __restrict__ ei32,
        const float* __restrict__ W0, const float* __restrict__ W1,
        const float* __restrict__ W2, int* __restrict__ flag,
        int* __restrict__ bcur, int* __restrict__ dhist, __half* __restrict__ Wt) {
    if (blockIdx.x == 0) {
        __shared__ int nz;
        if (threadIdx.x == 0) nz = 0;
        __syncthreads();
        int c = 0;
        for (int i = threadIdx.x; i < 1024; i += blockDim.x) {
            if (ei32[2 * i + 1] != 0) c++;   // int64 layout: high words all 0
        }
        atomicAdd(&nz, c);
        bcur[threadIdx.x] = threadIdx.x * CAP;   // fixed bucket bases
        dhist[threadIdx.x] = 0;
        __syncthreads();
        if (threadIdx.x == 0) *flag = (nz == 0) ? 1 : 0;  // 1 => int64
        return;
    }
    int bb = blockIdx.x - 1;                  // 48 blocks: 16 per weight
    int which = bb >> 4;
    const float* W = (which == 0) ? W0 : (which == 1) ? W1 : W2;
    __half* dst = Wt + (size_t)which * D * D;
    int tid = (bb & 15) * 256 + threadIdx.x;  // 4096 per weight
    int c  = tid >> 5;
    int k4 = (tid & 31) * 4;
    float w0 = W[(k4 + 0) * D + c];
    float w1 = W[(k4 + 1) * D + c];
    float w2 = W[(k4 + 2) * D + c];
    float w3 = W[(k4 + 3) * D + c];
    union { __half2 h2[2]; uint2 u; } pk;
    pk.h2[0] = __floats2half2_rn(w0, w1);
    pk.h2[1] = __floats2half2_rn(w2, w3);
    *(uint2*)&dst[(size_t)c * D + k4] = pk.u;
}

__device__ __forceinline__ int e_src(const void* ei, int e, int is64, int E) {
    return is64 ? (int)((const long long*)ei)[e] : ((const int*)ei)[e];
}
__device__ __forceinline__ int e_dst(const void* ei, int e, int is64, int E) {
    return is64 ? (int)((const long long*)ei)[E + e] : ((const int*)ei)[E + e];
}

// ---- binning: bucket-grouped (src,dst) at fixed bases b*CAP, contiguous runs ----
__global__ __launch_bounds__(256) void k_binning(const void* __restrict__ ei, int E,
        const int* __restrict__ flag, int* __restrict__ bcur, int2* __restrict__ ebuck) {
    __shared__ int lcnt[256];
    __shared__ int lbase[256];
    int is64 = *flag;
    int t = threadIdx.x;
    int e0 = blockIdx.x * BIN_CH;
    int e1 = min(e0 + BIN_CH, E);
    lcnt[t] = 0;
    __syncthreads();
    for (int e = e0 + t; e < e1; e += 256) {
        int d = e_dst(ei, e, is64, E);
        atomicAdd(&lcnt[d >> 8], 1);
    }
    __syncthreads();
    int c = lcnt[t];
    if (c > 0) lbase[t] = atomicAdd(&bcur[t], c);
    __syncthreads();
    lcnt[t] = 0;
    __syncthreads();
    for (int e = e0 + t; e < e1; e += 256) {
        int s = e_src(ei, e, is64, E);
        int d = e_dst(ei, e, is64, E);
        int b = d >> 8;
        int idx = atomicAdd(&lcnt[b], 1);
        ebuck[lbase[b] + idx] = make_int2(s, d);
    }
}

// ---- bucket build: degrees -> row_start/deg/dinv + CSR scatter + degree histogram ----
__global__ __launch_bounds__(256) void k_bucket_build(const int2* __restrict__ ebuck,
        const int* __restrict__ bcur, int* __restrict__ row_start,
        unsigned short* __restrict__ deg, float* __restrict__ dinv,
        int* __restrict__ esrc, int* __restrict__ dhist, int N) {
    __shared__ int lcnt[256];
    __shared__ int sc[256];
    __shared__ int lbase2[256];
    int b = blockIdx.x;
    int t = threadIdx.x;
    int lo = b * CAP;
    int hi = bcur[b];          // lo + count
    lcnt[t] = 0;
    __syncthreads();
    for (int j = lo + t; j < hi; j += 256) {
        atomicAdd(&lcnt[ebuck[j].y & 255], 1);
    }
    __syncthreads();
    int cntv = lcnt[t];
    sc[t] = cntv;
    __syncthreads();
#pragma unroll
    for (int d = 1; d < 256; d <<= 1) {
        int tv = (t >= d) ? sc[t - d] : 0;
        __syncthreads();
        sc[t] += tv;
        __syncthreads();
    }
    lbase2[t] = lo + sc[t] - cntv;   // CSR start for node (b<<8)+t (bucket-local base)
    int node = (b << 8) + t;
    if (node < N) {
        row_start[node] = lbase2[t];
        deg[node] = (unsigned short)cntv;
        dinv[node] = rsqrtf((float)(cntv + 1));
        atomicAdd(&dhist[min(cntv, 255)], 1);
    }
    lcnt[t] = 0;
    __syncthreads();
    for (int j = lo + t; j < hi; j += 256) {
        int2 ed = ebuck[j];
        int c = ed.y & 255;
        int idx = atomicAdd(&lcnt[c], 1);
        esrc[lbase2[c] + idx] = ed.x;
    }
}

// ---- degree-bin scan (1 block): dcur = exclusive scan of dhist ----
__global__ __launch_bounds__(256) void k_deg_scan(const int* __restrict__ dhist,
                                                  int* __restrict__ dcur) {
    __shared__ int sh[256];
    int t = threadIdx.x;
    int v = dhist[t];
    sh[t] = v;
    __syncthreads();
#pragma unroll
    for (int d = 1; d < 256; d <<= 1) {
        int tv = (t >= d) ? sh[t - d] : 0;
        __syncthreads();
        sh[t] += tv;
        __syncthreads();
    }
    dcur[t] = sh[t] - v;   // exclusive
}

// ---- degree scatter: order[] = node ids grouped by degree ----
__global__ __launch_bounds__(256) void k_deg_scatter(const unsigned short* __restrict__ deg,
        int* __restrict__ dcur, int* __restrict__ order, int N) {
    int node = blockIdx.x * 256 + threadIdx.x;
    if (node >= N) return;
    int dv = min((int)deg[node], 255);
    int pos = atomicAdd(&dcur[dv], 1);
    order[pos] = node;
}

// --------- MFMA GEMM: h' = (x @ W) * dinv[row], fp16 out, CHUNKED [4][N][32] ---------
template<bool IN16>
__global__ __launch_bounds__(256) void k_gemm_mfma(const void* __restrict__ xin,
        const __half* __restrict__ Wt, const float* __restrict__ dinv,
        __half* __restrict__ h, int N) {
    __shared__ __align__(16) char Ab[128 * 256];   // 128 rows x 128 halves
    __shared__ __align__(16) char Bb[128 * 256];   // 128 cols x 128 halves (Wt)
    int t = threadIdx.x;
    int br = blockIdx.x * 128;

#pragma unroll
    for (int i = 0; i < 8; ++i) {
        int byte = (i * 256 + t) * 16;
        int c = byte >> 8;
        uint4 v = *(const uint4*)((const char*)Wt + byte);
        *(uint4*)(Bb + (byte ^ ((c & 7) << 4))) = v;
    }
    if (IN16) {
        // input is chunked fp16 [4][N][32]
        const char* xp = (const char*)xin;
#pragma unroll
        for (int i = 0; i < 8; ++i) {
            int byte = (i * 256 + t) * 16;
            int row = byte >> 8;
            int gr = br + row;
            int co = byte & 255;           // byte offset within the 256B logical row
            uint4 v = make_uint4(0, 0, 0, 0);
            if (gr < N) {
                int chunk = co >> 6;       // 64 bytes (32 halves) per chunk
                v = *(const uint4*)(xp + (size_t)chunk * N * 64 + (size_t)gr * 64 + (co & 63));
            }
            *(uint4*)(Ab + (byte ^ ((row & 7) << 4))) = v;
        }
    } else {
        const float* xp = (const float*)xin;
#pragma unroll
        for (int i = 0; i < 16; ++i) {
            int fid = i * 256 + t;
            int row = fid >> 5;
            int col4 = (fid & 31) * 4;
            int gr = br + row;
            float4 v = make_float4(0.f, 0.f, 0.f, 0.f);
            if (gr < N) v = *(const float4*)&xp[(size_t)gr * D + col4];
            union { __half2 h2[2]; uint2 u; } pk;
            pk.h2[0] = __floats2half2_rn(v.x, v.y);
            pk.h2[1] = __floats2half2_rn(v.z, v.w);
            int byte = row * 256 + col4 * 2;
            *(uint2*)(Ab + (byte ^ ((row & 7) << 4))) = pk.u;
        }
    }
    __syncthreads();

    int w = t >> 6;
    int l = t & 63;
    int lrow = l & 15;
    int g = l >> 4;
    f32x4 acc[2][8] = {};
    int arow0 = w * 32 + lrow;
    int arow1 = arow0 + 16;
#pragma unroll
    for (int ks = 0; ks < 8; ++ks) {
        int kb = ks * 32 + g * 8;
        f16x4 a0 = *(const f16x4*)(Ab + ((arow0 * 256 + kb) ^ ((arow0 & 7) << 4)));
        f16x4 a1 = *(const f16x4*)(Ab + ((arow1 * 256 + kb) ^ ((arow1 & 7) << 4)));
#pragma unroll
        for (int nj = 0; nj < 8; ++nj) {
            int bc = nj * 16 + lrow;
            f16x4 b = *(const f16x4*)(Bb + ((bc * 256 + kb) ^ ((bc & 7) << 4)));
            acc[0][nj] = __builtin_amdgcn_mfma_f32_16x16x16f16(a0, b, acc[0][nj], 0, 0, 0);
            acc[1][nj] = __builtin_amdgcn_mfma_f32_16x16x16f16(a1, b, acc[1][nj], 0, 0, 0);
        }
    }
    // epilogue: scale by dinv[row], store fp16 into chunk (nj>>1), col (nj&1)*16+lrow
#pragma unroll
    for (int mi = 0; mi < 2; ++mi) {
        int rbase = br + w * 32 + mi * 16 + g * 4;
#pragma unroll
        for (int r = 0; r < 4; ++r) {
            int gr = rbase + r;
            if (gr < N) {
                float sc = dinv[gr];
#pragma unroll
                for (int nj = 0; nj < 8; ++nj) {
                    size_t idx = (size_t)(nj >> 1) * N * 32 + (size_t)gr * 32
                               + (nj & 1) * 16 + lrow;
                    h[idx] = __float2half(acc[mi][nj][r] * sc);
                }
            }
        }
    }
}

// ------ aggregation (chunked, degree-sorted): relu(dinv*(sum h'[s]+h'[i])+bias) ------
// chunk = (blockIdx&7)>>1 -> XCD-pinned; node order grouped by degree -> no divergence.
__device__ __forceinline__ void acc_row(uint4 u, float* a) {
    float2 q;
    q = __half22float2(*(const __half2*)&u.x); a[0] += q.x; a[1] += q.y;
    q = __half22float2(*(const __half2*)&u.y); a[2] += q.x; a[3] += q.y;
    q = __half22float2(*(const __half2*)&u.z); a[4] += q.x; a[5] += q.y;
    q = __half22float2(*(const __half2*)&u.w); a[6] += q.x; a[7] += q.y;
}

template<int WRITE_F32>
__global__ __launch_bounds__(256) void k_agg(const __half* __restrict__ h,
        const int* __restrict__ row_start, const unsigned short* __restrict__ deg,
        const int* __restrict__ esrc, const int* __restrict__ order,
        const float* __restrict__ dinv, const float* __restrict__ bias,
        float* __restrict__ out, __half* __restrict__ act, int N) {
    int xcd   = blockIdx.x & 7;
    int chunk = xcd >> 1;
    int rank  = ((blockIdx.x >> 3) << 1) + (xcd & 1);   // 0..2K-1 within chunk
    int idx = rank * 64 + (threadIdx.x >> 2);
    int l4 = threadIdx.x & 3;
    if (idx >= N) return;
    int node = order[idx];
    float di = dinv[node];
    const uint4* hv = (const uint4*)(h + (size_t)chunk * N * 32);  // 4 uint4 per node-row
    int j0 = row_start[node];
    int j1 = j0 + deg[node];

    float a[8] = {};
    acc_row(hv[(size_t)node * 4 + l4], a);   // self-loop h'[node]

    int j = j0;
    for (; j + 8 <= j1; j += 8) {
        int s0 = esrc[j],     s1 = esrc[j + 1], s2 = esrc[j + 2], s3 = esrc[j + 3];
        int s4 = esrc[j + 4], s5 = esrc[j + 5], s6 = esrc[j + 6], s7 = esrc[j + 7];
        uint4 u0 = hv[(size_t)s0 * 4 + l4];
        uint4 u1 = hv[(size_t)s1 * 4 + l4];
        uint4 u2 = hv[(size_t)s2 * 4 + l4];
        uint4 u3 = hv[(size_t)s3 * 4 + l4];
        uint4 u4 = hv[(size_t)s4 * 4 + l4];
        uint4 u5 = hv[(size_t)s5 * 4 + l4];
        uint4 u6 = hv[(size_t)s6 * 4 + l4];
        uint4 u7 = hv[(size_t)s7 * 4 + l4];
        acc_row(u0, a); acc_row(u1, a); acc_row(u2, a); acc_row(u3, a);
        acc_row(u4, a); acc_row(u5, a); acc_row(u6, a); acc_row(u7, a);
    }
    for (; j + 4 <= j1; j += 4) {
        int s0 = esrc[j], s1 = esrc[j + 1], s2 = esrc[j + 2], s3 = esrc[j + 3];
        uint4 u0 = hv[(size_t)s0 * 4 + l4];
        uint4 u1 = hv[(size_t)s1 * 4 + l4];
        uint4 u2 = hv[(size_t)s2 * 4 + l4];
        uint4 u3 = hv[(size_t)s3 * 4 + l4];
        acc_row(u0, a); acc_row(u1, a); acc_row(u2, a); acc_row(u3, a);
    }
    for (; j < j1; ++j) {
        acc_row(hv[(size_t)esrc[j] * 4 + l4], a);
    }
    const float4* b4 = (const float4*)bias;
    float4 bv0 = b4[chunk * 8 + l4 * 2], bv1 = b4[chunk * 8 + l4 * 2 + 1];
    float o[8];
    o[0] = fmaxf(fmaf(a[0], di, bv0.x), 0.f);
    o[1] = fmaxf(fmaf(a[1], di, bv0.y), 0.f);
    o[2] = fmaxf(fmaf(a[2], di, bv0.z), 0.f);
    o[3] = fmaxf(fmaf(a[3], di, bv0.w), 0.f);
    o[4] = fmaxf(fmaf(a[4], di, bv1.x), 0.f);
    o[5] = fmaxf(fmaf(a[5], di, bv1.y), 0.f);
    o[6] = fmaxf(fmaf(a[6], di, bv1.z), 0.f);
    o[7] = fmaxf(fmaf(a[7], di, bv1.w), 0.f);
    if (WRITE_F32) {
        float4* o4 = (float4*)out;   // row-major final output, 32-col slice
        o4[(size_t)node * 32 + chunk * 8 + l4 * 2]     = make_float4(o[0], o[1], o[2], o[3]);
        o4[(size_t)node * 32 + chunk * 8 + l4 * 2 + 1] = make_float4(o[4], o[5], o[6], o[7]);
    } else {
        union { __half2 h2[4]; uint4 u; } pk;
        pk.h2[0] = __floats2half2_rn(o[0], o[1]);
        pk.h2[1] = __floats2half2_rn(o[2], o[3]);
        pk.h2[2] = __floats2half2_rn(o[4], o[5]);
        pk.h2[3] = __floats2half2_rn(o[6], o[7]);
        ((uint4*)act)[(size_t)chunk * N * 4 + (size_t)node * 4 + l4] = pk.u;  // chunked act
    }
}

// ---------------- host launch ----------------
extern "C" void kernel_launch(void* const* d_in, const int* in_sizes, int n_in,
                              void* d_out, int out_size, void* d_ws, size_t ws_size,
                              hipStream_t stream) {
    const float* x  = (const float*)d_in[0];
    const void*  ei = d_in[1];
    const float* W0 = (const float*)d_in[2];
    const float* b0 = (const float*)d_in[3];
    const float* W1 = (const float*)d_in[4];
    const float* b1 = (const float*)d_in[5];
    const float* W2 = (const float*)d_in[6];
    const float* b2 = (const float*)d_in[7];
    float* out = (float*)d_out;

    const int N = in_sizes[0] / D;       // 50000
    const int E = in_sizes[1] / 2;       // 800000

    char* ws = (char*)d_ws;
    size_t off = 0;
    auto alloc = [&](size_t bytes) {
        char* p = ws + off;
        off = (off + bytes + 255) & ~(size_t)255;
        return p;
    };
    int*            flag      = (int*)alloc(4);
    int*            bcur      = (int*)alloc(256 * 4);
    int*            dhist     = (int*)alloc(256 * 4);
    int*            dcur      = (int*)alloc(256 * 4);
    int*            row_start = (int*)alloc((size_t)N * 4);
    unsigned short* deg       = (unsigned short*)alloc((size_t)N * 2);
    float*          dinv      = (float*)alloc((size_t)N * 4);
    int*            order     = (int*)alloc((size_t)N * 4);
    int*            esrc      = (int*)alloc((size_t)256 * CAP * 4);
    __half*         hbuf      = (__half*)alloc((size_t)N * D * 2);   // chunked [4][N][32]
    __half*         act       = (__half*)alloc((size_t)N * D * 2);   // chunked [4][N][32]
    __half*         Wt        = (__half*)alloc((size_t)3 * D * D * 2);
    // ebuck (196*CAP*8B = 9.6MB) aliases hbuf (12.8MB): graph build completes
    // before the first GEMM writes hbuf, stream-ordered.
    int2*           ebuck     = (int2*)hbuf;
    (void)ws_size;

    const int nbuck = (N + 255) >> 8;        // 196
    const int nbin  = (E + BIN_CH - 1) / BIN_CH;

    // init -> binning -> bucket build (+deg hist) -> deg scan -> deg scatter
    k_init<<<49, 256, 0, stream>>>((const int*)ei, W0, W1, W2, flag, bcur, dhist, Wt);
    k_binning<<<nbin, 256, 0, stream>>>(ei, E, flag, bcur, ebuck);
    k_bucket_build<<<nbuck, 256, 0, stream>>>(ebuck, bcur, row_start, deg, dinv, esrc, dhist, N);
    k_deg_scan<<<1, 256, 0, stream>>>(dhist, dcur);
    k_deg_scatter<<<nbuck, 256, 0, stream>>>(deg, dcur, order, N);

    const int gemm_grid = (N + 127) / 128;           // 391
    const int ranks     = (N + 63) / 64;             // 782 (64 nodes/block)
    const int aggB      = (((ranks + 1) / 2)) * 8;   // 8 XCD groups x K

    // layer 0: x(f32) -> hbuf -> act(fp16)
    k_gemm_mfma<false><<<gemm_grid, 256, 0, stream>>>(x, Wt, dinv, hbuf, N);
    k_agg<0><<<aggB, 256, 0, stream>>>(hbuf, row_start, deg, esrc, order, dinv, b0, out, act, N);
    // layer 1: act -> hbuf -> act
    k_gemm_mfma<true><<<gemm_grid, 256, 0, stream>>>(act, Wt + (size_t)D * D, dinv, hbuf, N);
    k_agg<0><<<aggB, 256, 0, stream>>>(hbuf, row_start, deg, esrc, order, dinv, b1, out, act, N);
    // layer 2: act -> hbuf -> out(f32)
    k_gemm_mfma<true><<<gemm_grid, 256, 0, stream>>>(act, Wt + (size_t)2 * D * D, dinv, hbuf, N);
    k_agg<1><<<aggB, 256, 0, stream>>>(hbuf, row_start, deg, esrc, order, dinv, b2, out, act, N);
}

// Round 12
// 196.473 us; speedup vs baseline: 2.3309x; 2.3309x over previous
//
#include <hip/hip_runtime.h>
#include <hip/hip_fp16.h>

#define D 128
#define BIN_CH 8192
#define CAP 6144   // per-bucket edge capacity (mean 4081, sigma ~64 -> 32-sigma headroom)

typedef _Float16 f16x4 __attribute__((ext_vector_type(4)));
typedef float f32x4 __attribute__((ext_vector_type(4)));

// ---- k_init: block 0 = dtype-detect + bcur init; blocks 1..48 = W transpose->fp16 ----
__global__ __launch_bounds__(256) void k_init(const int* __restrict__ ei32,
        const float* __restrict__ W0, const float* __restrict__ W1,
        const float* __restrict__ W2, int* __restrict__ flag,
        int* __restrict__ bcur, __half* __restrict__ Wt) {
    if (blockIdx.x == 0) {
        __shared__ int nz;
        if (threadIdx.x == 0) nz = 0;
        __syncthreads();
        int c = 0;
        for (int i = threadIdx.x; i < 1024; i += blockDim.x) {
            if (ei32[2 * i + 1] != 0) c++;   // int64 layout: high words all 0
        }
        atomicAdd(&nz, c);
        bcur[threadIdx.x] = threadIdx.x * CAP;   // fixed bucket bases
        __syncthreads();
        if (threadIdx.x == 0) *flag = (nz == 0) ? 1 : 0;  // 1 => int64
        return;
    }
    int bb = blockIdx.x - 1;                  // 48 blocks: 16 per weight
    int which = bb >> 4;
    const float* W = (which == 0) ? W0 : (which == 1) ? W1 : W2;
    __half* dst = Wt + (size_t)which * D * D;
    int tid = (bb & 15) * 256 + threadIdx.x;  // 4096 per weight
    int c  = tid >> 5;
    int k4 = (tid & 31) * 4;
    float w0 = W[(k4 + 0) * D + c];
    float w1 = W[(k4 + 1) * D + c];
    float w2 = W[(k4 + 2) * D + c];
    float w3 = W[(k4 + 3) * D + c];
    union { __half2 h2[2]; uint2 u; } pk;
    pk.h2[0] = __floats2half2_rn(w0, w1);
    pk.h2[1] = __floats2half2_rn(w2, w3);
    *(uint2*)&dst[(size_t)c * D + k4] = pk.u;
}

__device__ __forceinline__ int e_src(const void* ei, int e, int is64, int E) {
    return is64 ? (int)((const long long*)ei)[e] : ((const int*)ei)[e];
}
__device__ __forceinline__ int e_dst(const void* ei, int e, int is64, int E) {
    return is64 ? (int)((const long long*)ei)[E + e] : ((const int*)ei)[E + e];
}

// ---- binning: bucket-grouped (src,dst) at fixed bases b*CAP, contiguous runs ----
__global__ __launch_bounds__(256) void k_binning(const void* __restrict__ ei, int E,
        const int* __restrict__ flag, int* __restrict__ bcur, int2* __restrict__ ebuck) {
    __shared__ int lcnt[256];
    __shared__ int lbase[256];
    int is64 = *flag;
    int t = threadIdx.x;
    int e0 = blockIdx.x * BIN_CH;
    int e1 = min(e0 + BIN_CH, E);
    lcnt[t] = 0;
    __syncthreads();
    for (int e = e0 + t; e < e1; e += 256) {
        int d = e_dst(ei, e, is64, E);
        atomicAdd(&lcnt[d >> 8], 1);
    }
    __syncthreads();
    int c = lcnt[t];
    if (c > 0) lbase[t] = atomicAdd(&bcur[t], c);
    __syncthreads();
    lcnt[t] = 0;
    __syncthreads();
    for (int e = e0 + t; e < e1; e += 256) {
        int s = e_src(ei, e, is64, E);
        int d = e_dst(ei, e, is64, E);
        int b = d >> 8;
        int idx = atomicAdd(&lcnt[b], 1);
        ebuck[lbase[b] + idx] = make_int2(s, d);
    }
}

// ---- bucket build: degrees -> row_start/deg/dinv + CSR scatter + BUCKET-LOCAL deg sort ----
__global__ __launch_bounds__(256) void k_bucket_build(const int2* __restrict__ ebuck,
        const int* __restrict__ bcur, int* __restrict__ row_start,
        unsigned short* __restrict__ deg, float* __restrict__ dinv,
        int* __restrict__ esrc, int* __restrict__ order, int N) {
    __shared__ int lcnt[256];
    __shared__ int sc[256];
    __shared__ int lbase2[256];
    __shared__ int dg[256];
    int b = blockIdx.x;
    int t = threadIdx.x;
    int lo = b * CAP;
    int hi = bcur[b];          // lo + count
    lcnt[t] = 0;
    __syncthreads();
    for (int j = lo + t; j < hi; j += 256) {
        atomicAdd(&lcnt[ebuck[j].y & 255], 1);
    }
    __syncthreads();
    int cntv = lcnt[t];
    sc[t] = cntv;
    int node = (b << 8) + t;
    int myd = (node < N) ? cntv : 0x7FFFFFFF;   // phantoms sort last
    dg[t] = myd;
    __syncthreads();
#pragma unroll
    for (int d = 1; d < 256; d <<= 1) {
        int tv = (t >= d) ? sc[t - d] : 0;
        __syncthreads();
        sc[t] += tv;
        __syncthreads();
    }
    lbase2[t] = lo + sc[t] - cntv;   // CSR start for node (b<<8)+t (bucket-local base)
    if (node < N) {
        row_start[node] = lbase2[t];
        deg[node] = (unsigned short)cntv;
        dinv[node] = rsqrtf((float)(cntv + 1));
    }
    // bucket-local rank sort by degree (ties by thread id) -> order[]
    int rank = 0;
#pragma unroll 8
    for (int u = 0; u < 256; ++u) {
        int dv = dg[u];
        rank += (dv < myd) || (dv == myd && u < t);
    }
    if (node < N) order[(b << 8) + rank] = node;
    lcnt[t] = 0;
    __syncthreads();
    for (int j = lo + t; j < hi; j += 256) {
        int2 ed = ebuck[j];
        int c = ed.y & 255;
        int idx = atomicAdd(&lcnt[c], 1);
        esrc[lbase2[c] + idx] = ed.x;
    }
}

// --------- MFMA GEMM: h' = (x @ W) * dinv[row], fp16 out, CHUNKED [4][N][32] ---------
template<bool IN16>
__global__ __launch_bounds__(256) void k_gemm_mfma(const void* __restrict__ xin,
        const __half* __restrict__ Wt, const float* __restrict__ dinv,
        __half* __restrict__ h, int N) {
    __shared__ __align__(16) char Ab[128 * 256];   // 128 rows x 128 halves
    __shared__ __align__(16) char Bb[128 * 256];   // 128 cols x 128 halves (Wt)
    int t = threadIdx.x;
    int br = blockIdx.x * 128;

#pragma unroll
    for (int i = 0; i < 8; ++i) {
        int byte = (i * 256 + t) * 16;
        int c = byte >> 8;
        uint4 v = *(const uint4*)((const char*)Wt + byte);
        *(uint4*)(Bb + (byte ^ ((c & 7) << 4))) = v;
    }
    if (IN16) {
        // input is chunked fp16 [4][N][32]
        const char* xp = (const char*)xin;
#pragma unroll
        for (int i = 0; i < 8; ++i) {
            int byte = (i * 256 + t) * 16;
            int row = byte >> 8;
            int gr = br + row;
            int co = byte & 255;           // byte offset within the 256B logical row
            uint4 v = make_uint4(0, 0, 0, 0);
            if (gr < N) {
                int chunk = co >> 6;       // 64 bytes (32 halves) per chunk
                v = *(const uint4*)(xp + (size_t)chunk * N * 64 + (size_t)gr * 64 + (co & 63));
            }
            *(uint4*)(Ab + (byte ^ ((row & 7) << 4))) = v;
        }
    } else {
        const float* xp = (const float*)xin;
#pragma unroll
        for (int i = 0; i < 16; ++i) {
            int fid = i * 256 + t;
            int row = fid >> 5;
            int col4 = (fid & 31) * 4;
            int gr = br + row;
            float4 v = make_float4(0.f, 0.f, 0.f, 0.f);
            if (gr < N) v = *(const float4*)&xp[(size_t)gr * D + col4];
            union { __half2 h2[2]; uint2 u; } pk;
            pk.h2[0] = __floats2half2_rn(v.x, v.y);
            pk.h2[1] = __floats2half2_rn(v.z, v.w);
            int byte = row * 256 + col4 * 2;
            *(uint2*)(Ab + (byte ^ ((row & 7) << 4))) = pk.u;
        }
    }
    __syncthreads();

    int w = t >> 6;
    int l = t & 63;
    int lrow = l & 15;
    int g = l >> 4;
    f32x4 acc[2][8] = {};
    int arow0 = w * 32 + lrow;
    int arow1 = arow0 + 16;
#pragma unroll
    for (int ks = 0; ks < 8; ++ks) {
        int kb = ks * 32 + g * 8;
        f16x4 a0 = *(const f16x4*)(Ab + ((arow0 * 256 + kb) ^ ((arow0 & 7) << 4)));
        f16x4 a1 = *(const f16x4*)(Ab + ((arow1 * 256 + kb) ^ ((arow1 & 7) << 4)));
#pragma unroll
        for (int nj = 0; nj < 8; ++nj) {
            int bc = nj * 16 + lrow;
            f16x4 b = *(const f16x4*)(Bb + ((bc * 256 + kb) ^ ((bc & 7) << 4)));
            acc[0][nj] = __builtin_amdgcn_mfma_f32_16x16x16f16(a0, b, acc[0][nj], 0, 0, 0);
            acc[1][nj] = __builtin_amdgcn_mfma_f32_16x16x16f16(a1, b, acc[1][nj], 0, 0, 0);
        }
    }
    // epilogue: scale by dinv[row], store fp16 into chunk (nj>>1), col (nj&1)*16+lrow
#pragma unroll
    for (int mi = 0; mi < 2; ++mi) {
        int rbase = br + w * 32 + mi * 16 + g * 4;
#pragma unroll
        for (int r = 0; r < 4; ++r) {
            int gr = rbase + r;
            if (gr < N) {
                float sc = dinv[gr];
#pragma unroll
                for (int nj = 0; nj < 8; ++nj) {
                    size_t idx = (size_t)(nj >> 1) * N * 32 + (size_t)gr * 32
                               + (nj & 1) * 16 + lrow;
                    h[idx] = __float2half(acc[mi][nj][r] * sc);
                }
            }
        }
    }
}

// ------ aggregation (chunked, bucket-local degree-sorted) ------
// chunk = (blockIdx&7)>>1 -> XCD-pinned; order[] groups same-degree nodes per bucket.
__device__ __forceinline__ void acc_row(uint4 u, float* a) {
    float2 q;
    q = __half22float2(*(const __half2*)&u.x); a[0] += q.x; a[1] += q.y;
    q = __half22float2(*(const __half2*)&u.y); a[2] += q.x; a[3] += q.y;
    q = __half22float2(*(const __half2*)&u.z); a[4] += q.x; a[5] += q.y;
    q = __half22float2(*(const __half2*)&u.w); a[6] += q.x; a[7] += q.y;
}

template<int WRITE_F32>
__global__ __launch_bounds__(256) void k_agg(const __half* __restrict__ h,
        const int* __restrict__ row_start, const unsigned short* __restrict__ deg,
        const int* __restrict__ esrc, const int* __restrict__ order,
        const float* __restrict__ dinv, const float* __restrict__ bias,
        float* __restrict__ out, __half* __restrict__ act, int N) {
    int xcd   = blockIdx.x & 7;
    int chunk = xcd >> 1;
    int rank  = ((blockIdx.x >> 3) << 1) + (xcd & 1);   // 0..2K-1 within chunk
    int idx = rank * 64 + (threadIdx.x >> 2);
    int l4 = threadIdx.x & 3;
    if (idx >= N) return;
    int node = order[idx];
    float di = dinv[node];
    const uint4* hv = (const uint4*)(h + (size_t)chunk * N * 32);  // 4 uint4 per node-row
    int j0 = row_start[node];
    int j1 = j0 + deg[node];

    float a[8] = {};
    acc_row(hv[(size_t)node * 4 + l4], a);   // self-loop h'[node]

    int j = j0;
    for (; j + 8 <= j1; j += 8) {
        int s0 = esrc[j],     s1 = esrc[j + 1], s2 = esrc[j + 2], s3 = esrc[j + 3];
        int s4 = esrc[j + 4], s5 = esrc[j + 5], s6 = esrc[j + 6], s7 = esrc[j + 7];
        uint4 u0 = hv[(size_t)s0 * 4 + l4];
        uint4 u1 = hv[(size_t)s1 * 4 + l4];
        uint4 u2 = hv[(size_t)s2 * 4 + l4];
        uint4 u3 = hv[(size_t)s3 * 4 + l4];
        uint4 u4 = hv[(size_t)s4 * 4 + l4];
        uint4 u5 = hv[(size_t)s5 * 4 + l4];
        uint4 u6 = hv[(size_t)s6 * 4 + l4];
        uint4 u7 = hv[(size_t)s7 * 4 + l4];
        acc_row(u0, a); acc_row(u1, a); acc_row(u2, a); acc_row(u3, a);
        acc_row(u4, a); acc_row(u5, a); acc_row(u6, a); acc_row(u7, a);
    }
    for (; j + 4 <= j1; j += 4) {
        int s0 = esrc[j], s1 = esrc[j + 1], s2 = esrc[j + 2], s3 = esrc[j + 3];
        uint4 u0 = hv[(size_t)s0 * 4 + l4];
        uint4 u1 = hv[(size_t)s1 * 4 + l4];
        uint4 u2 = hv[(size_t)s2 * 4 + l4];
        uint4 u3 = hv[(size_t)s3 * 4 + l4];
        acc_row(u0, a); acc_row(u1, a); acc_row(u2, a); acc_row(u3, a);
    }
    for (; j < j1; ++j) {
        acc_row(hv[(size_t)esrc[j] * 4 + l4], a);
    }
    const float4* b4 = (const float4*)bias;
    float4 bv0 = b4[chunk * 8 + l4 * 2], bv1 = b4[chunk * 8 + l4 * 2 + 1];
    float o[8];
    o[0] = fmaxf(fmaf(a[0], di, bv0.x), 0.f);
    o[1] = fmaxf(fmaf(a[1], di, bv0.y), 0.f);
    o[2] = fmaxf(fmaf(a[2], di, bv0.z), 0.f);
    o[3] = fmaxf(fmaf(a[3], di, bv0.w), 0.f);
    o[4] = fmaxf(fmaf(a[4], di, bv1.x), 0.f);
    o[5] = fmaxf(fmaf(a[5], di, bv1.y), 0.f);
    o[6] = fmaxf(fmaf(a[6], di, bv1.z), 0.f);
    o[7] = fmaxf(fmaf(a[7], di, bv1.w), 0.f);
    if (WRITE_F32) {
        float4* o4 = (float4*)out;   // row-major final output, 32-col slice
        o4[(size_t)node * 32 + chunk * 8 + l4 * 2]     = make_float4(o[0], o[1], o[2], o[3]);
        o4[(size_t)node * 32 + chunk * 8 + l4 * 2 + 1] = make_float4(o[4], o[5], o[6], o[7]);
    } else {
        union { __half2 h2[4]; uint4 u; } pk;
        pk.h2[0] = __floats2half2_rn(o[0], o[1]);
        pk.h2[1] = __floats2half2_rn(o[2], o[3]);
        pk.h2[2] = __floats2half2_rn(o[4], o[5]);
        pk.h2[3] = __floats2half2_rn(o[6], o[7]);
        ((uint4*)act)[(size_t)chunk * N * 4 + (size_t)node * 4 + l4] = pk.u;  // chunked act
    }
}

// ---------------- host launch ----------------
extern "C" void kernel_launch(void* const* d_in, const int* in_sizes, int n_in,
                              void* d_out, int out_size, void* d_ws, size_t ws_size,
                              hipStream_t stream) {
    const float* x  = (const float*)d_in[0];
    const void*  ei = d_in[1];
    const float* W0 = (const float*)d_in[2];
    const float* b0 = (const float*)d_in[3];
    const float* W1 = (const float*)d_in[4];
    const float* b1 = (const float*)d_in[5];
    const float* W2 = (const float*)d_in[6];
    const float* b2 = (const float*)d_in[7];
    float* out = (float*)d_out;

    const int N = in_sizes[0] / D;       // 50000
    const int E = in_sizes[1] / 2;       // 800000

    char* ws = (char*)d_ws;
    size_t off = 0;
    auto alloc = [&](size_t bytes) {
        char* p = ws + off;
        off = (off + bytes + 255) & ~(size_t)255;
        return p;
    };
    int*            flag      = (int*)alloc(4);
    int*            bcur      = (int*)alloc(256 * 4);
    int*            row_start = (int*)alloc((size_t)N * 4);
    unsigned short* deg       = (unsigned short*)alloc((size_t)N * 2);
    float*          dinv      = (float*)alloc((size_t)N * 4);
    int*            order     = (int*)alloc((size_t)N * 4);
    int*            esrc      = (int*)alloc((size_t)256 * CAP * 4);
    __half*         hbuf      = (__half*)alloc((size_t)N * D * 2);   // chunked [4][N][32]
    __half*         act       = (__half*)alloc((size_t)N * D * 2);   // chunked [4][N][32]
    __half*         Wt        = (__half*)alloc((size_t)3 * D * D * 2);
    // ebuck (196*CAP*8B = 9.6MB) aliases hbuf (12.8MB): graph build completes
    // before the first GEMM writes hbuf, stream-ordered.
    int2*           ebuck     = (int2*)hbuf;
    (void)ws_size;

    const int nbuck = (N + 255) >> 8;        // 196
    const int nbin  = (E + BIN_CH - 1) / BIN_CH;

    // init -> binning -> bucket build (CSR + bucket-local degree sort)
    k_init<<<49, 256, 0, stream>>>((const int*)ei, W0, W1, W2, flag, bcur, Wt);
    k_binning<<<nbin, 256, 0, stream>>>(ei, E, flag, bcur, ebuck);
    k_bucket_build<<<nbuck, 256, 0, stream>>>(ebuck, bcur, row_start, deg, dinv, esrc, order, N);

    const int gemm_grid = (N + 127) / 128;           // 391
    const int ranks     = (N + 63) / 64;             // 782 (64 nodes/block)
    const int aggB      = (((ranks + 1) / 2)) * 8;   // 8 XCD groups x K

    // layer 0: x(f32) -> hbuf -> act(fp16)
    k_gemm_mfma<false><<<gemm_grid, 256, 0, stream>>>(x, Wt, dinv, hbuf, N);
    k_agg<0><<<aggB, 256, 0, stream>>>(hbuf, row_start, deg, esrc, order, dinv, b0, out, act, N);
    // layer 1: act -> hbuf -> act
    k_gemm_mfma<true><<<gemm_grid, 256, 0, stream>>>(act, Wt + (size_t)D * D, dinv, hbuf, N);
    k_agg<0><<<aggB, 256, 0, stream>>>(hbuf, row_start, deg, esrc, order, dinv, b1, out, act, N);
    // layer 2: act -> hbuf -> out(f32)
    k_gemm_mfma<true><<<gemm_grid, 256, 0, stream>>>(act, Wt + (size_t)2 * D * D, dinv, hbuf, N);
    k_agg<1><<<aggB, 256, 0, stream>>>(hbuf, row_start, deg, esrc, order, dinv, b2, out, act, N);
}

// Round 13
// 177.150 us; speedup vs baseline: 2.5852x; 1.1091x over previous
//
#include <hip/hip_runtime.h>
#include <hip/hip_fp16.h>

#define D 128
#define BIN_CH 8192
#define CAP 6144   // per-bucket edge capacity (mean 4081, sigma ~64 -> 32-sigma headroom)

typedef _Float16 f16x4 __attribute__((ext_vector_type(4)));
typedef float f32x4 __attribute__((ext_vector_type(4)));

// ---- k_init: block 0 = dtype-detect + bcur init; blocks 1..48 = W transpose->fp16 ----
__global__ __launch_bounds__(256) void k_init(const int* __restrict__ ei32,
        const float* __restrict__ W0, const float* __restrict__ W1,
        const float* __restrict__ W2, int* __restrict__ flag,
        int* __restrict__ bcur, __half* __restrict__ Wt) {
    if (blockIdx.x == 0) {
        __shared__ int nz;
        if (threadIdx.x == 0) nz = 0;
        __syncthreads();
        int c = 0;
        for (int i = threadIdx.x; i < 1024; i += blockDim.x) {
            if (ei32[2 * i + 1] != 0) c++;   // int64 layout: high words all 0
        }
        atomicAdd(&nz, c);
        bcur[threadIdx.x] = threadIdx.x * CAP;   // fixed bucket bases
        __syncthreads();
        if (threadIdx.x == 0) *flag = (nz == 0) ? 1 : 0;  // 1 => int64
        return;
    }
    int bb = blockIdx.x - 1;                  // 48 blocks: 16 per weight
    int which = bb >> 4;
    const float* W = (which == 0) ? W0 : (which == 1) ? W1 : W2;
    __half* dst = Wt + (size_t)which * D * D;
    int tid = (bb & 15) * 256 + threadIdx.x;  // 4096 per weight
    int c  = tid >> 5;
    int k4 = (tid & 31) * 4;
    float w0 = W[(k4 + 0) * D + c];
    float w1 = W[(k4 + 1) * D + c];
    float w2 = W[(k4 + 2) * D + c];
    float w3 = W[(k4 + 3) * D + c];
    union { __half2 h2[2]; uint2 u; } pk;
    pk.h2[0] = __floats2half2_rn(w0, w1);
    pk.h2[1] = __floats2half2_rn(w2, w3);
    *(uint2*)&dst[(size_t)c * D + k4] = pk.u;
}

__device__ __forceinline__ int e_src(const void* ei, int e, int is64, int E) {
    return is64 ? (int)((const long long*)ei)[e] : ((const int*)ei)[e];
}
__device__ __forceinline__ int e_dst(const void* ei, int e, int is64, int E) {
    return is64 ? (int)((const long long*)ei)[E + e] : ((const int*)ei)[E + e];
}

// ---- binning: bucket-grouped (src,dst) at fixed bases b*CAP, contiguous runs ----
__global__ __launch_bounds__(256) void k_binning(const void* __restrict__ ei, int E,
        const int* __restrict__ flag, int* __restrict__ bcur, int2* __restrict__ ebuck) {
    __shared__ int lcnt[256];
    __shared__ int lbase[256];
    int is64 = *flag;
    int t = threadIdx.x;
    int e0 = blockIdx.x * BIN_CH;
    int e1 = min(e0 + BIN_CH, E);
    lcnt[t] = 0;
    __syncthreads();
    for (int e = e0 + t; e < e1; e += 256) {
        int d = e_dst(ei, e, is64, E);
        atomicAdd(&lcnt[d >> 8], 1);
    }
    __syncthreads();
    int c = lcnt[t];
    if (c > 0) lbase[t] = atomicAdd(&bcur[t], c);
    __syncthreads();
    lcnt[t] = 0;
    __syncthreads();
    for (int e = e0 + t; e < e1; e += 256) {
        int s = e_src(ei, e, is64, E);
        int d = e_dst(ei, e, is64, E);
        int b = d >> 8;
        int idx = atomicAdd(&lcnt[b], 1);
        ebuck[lbase[b] + idx] = make_int2(s, d);
    }
}

// ---- bucket build: per-bucket degrees -> row_start/deg/dinv + in-segment CSR scatter ----
__global__ __launch_bounds__(256) void k_bucket_build(const int2* __restrict__ ebuck,
        const int* __restrict__ bcur, int* __restrict__ row_start,
        unsigned short* __restrict__ deg, float* __restrict__ dinv,
        int* __restrict__ esrc, int N) {
    __shared__ int lcnt[256];
    __shared__ int sc[256];
    __shared__ int lbase2[256];
    int b = blockIdx.x;
    int t = threadIdx.x;
    int lo = b * CAP;
    int hi = bcur[b];          // lo + count
    lcnt[t] = 0;
    __syncthreads();
    for (int j = lo + t; j < hi; j += 256) {
        atomicAdd(&lcnt[ebuck[j].y & 255], 1);
    }
    __syncthreads();
    int cntv = lcnt[t];
    sc[t] = cntv;
    __syncthreads();
#pragma unroll
    for (int d = 1; d < 256; d <<= 1) {
        int tv = (t >= d) ? sc[t - d] : 0;
        __syncthreads();
        sc[t] += tv;
        __syncthreads();
    }
    lbase2[t] = lo + sc[t] - cntv;   // CSR start for node (b<<8)+t (bucket-local base)
    int node = (b << 8) + t;
    if (node < N) {
        row_start[node] = lbase2[t];
        deg[node] = (unsigned short)cntv;
        dinv[node] = rsqrtf((float)(cntv + 1));
    }
    lcnt[t] = 0;
    __syncthreads();
    for (int j = lo + t; j < hi; j += 256) {
        int2 ed = ebuck[j];
        int c = ed.y & 255;
        int idx = atomicAdd(&lcnt[c], 1);
        esrc[lbase2[c] + idx] = ed.x;
    }
}

// --------- MFMA GEMM: h' = (x @ W) * dinv[row], fp16 out, CHUNKED [4][N][32] ---------
template<bool IN16>
__global__ __launch_bounds__(256) void k_gemm_mfma(const void* __restrict__ xin,
        const __half* __restrict__ Wt, const float* __restrict__ dinv,
        __half* __restrict__ h, int N) {
    __shared__ __align__(16) char Ab[128 * 256];   // 128 rows x 128 halves
    __shared__ __align__(16) char Bb[128 * 256];   // 128 cols x 128 halves (Wt)
    int t = threadIdx.x;
    int br = blockIdx.x * 128;

#pragma unroll
    for (int i = 0; i < 8; ++i) {
        int byte = (i * 256 + t) * 16;
        int c = byte >> 8;
        uint4 v = *(const uint4*)((const char*)Wt + byte);
        *(uint4*)(Bb + (byte ^ ((c & 7) << 4))) = v;
    }
    if (IN16) {
        // input is chunked fp16 [4][N][32]
        const char* xp = (const char*)xin;
#pragma unroll
        for (int i = 0; i < 8; ++i) {
            int byte = (i * 256 + t) * 16;
            int row = byte >> 8;
            int gr = br + row;
            int co = byte & 255;           // byte offset within the 256B logical row
            uint4 v = make_uint4(0, 0, 0, 0);
            if (gr < N) {
                int chunk = co >> 6;       // 64 bytes (32 halves) per chunk
                v = *(const uint4*)(xp + (size_t)chunk * N * 64 + (size_t)gr * 64 + (co & 63));
            }
            *(uint4*)(Ab + (byte ^ ((row & 7) << 4))) = v;
        }
    } else {
        const float* xp = (const float*)xin;
#pragma unroll
        for (int i = 0; i < 16; ++i) {
            int fid = i * 256 + t;
            int row = fid >> 5;
            int col4 = (fid & 31) * 4;
            int gr = br + row;
            float4 v = make_float4(0.f, 0.f, 0.f, 0.f);
            if (gr < N) v = *(const float4*)&xp[(size_t)gr * D + col4];
            union { __half2 h2[2]; uint2 u; } pk;
            pk.h2[0] = __floats2half2_rn(v.x, v.y);
            pk.h2[1] = __floats2half2_rn(v.z, v.w);
            int byte = row * 256 + col4 * 2;
            *(uint2*)(Ab + (byte ^ ((row & 7) << 4))) = pk.u;
        }
    }
    __syncthreads();

    int w = t >> 6;
    int l = t & 63;
    int lrow = l & 15;
    int g = l >> 4;
    f32x4 acc[2][8] = {};
    int arow0 = w * 32 + lrow;
    int arow1 = arow0 + 16;
#pragma unroll
    for (int ks = 0; ks < 8; ++ks) {
        int kb = ks * 32 + g * 8;
        f16x4 a0 = *(const f16x4*)(Ab + ((arow0 * 256 + kb) ^ ((arow0 & 7) << 4)));
        f16x4 a1 = *(const f16x4*)(Ab + ((arow1 * 256 + kb) ^ ((arow1 & 7) << 4)));
#pragma unroll
        for (int nj = 0; nj < 8; ++nj) {
            int bc = nj * 16 + lrow;
            f16x4 b = *(const f16x4*)(Bb + ((bc * 256 + kb) ^ ((bc & 7) << 4)));
            acc[0][nj] = __builtin_amdgcn_mfma_f32_16x16x16f16(a0, b, acc[0][nj], 0, 0, 0);
            acc[1][nj] = __builtin_amdgcn_mfma_f32_16x16x16f16(a1, b, acc[1][nj], 0, 0, 0);
        }
    }
    // epilogue: scale by dinv[row], store fp16 into chunk (nj>>1), col (nj&1)*16+lrow
#pragma unroll
    for (int mi = 0; mi < 2; ++mi) {
        int rbase = br + w * 32 + mi * 16 + g * 4;
#pragma unroll
        for (int r = 0; r < 4; ++r) {
            int gr = rbase + r;
            if (gr < N) {
                float sc = dinv[gr];
#pragma unroll
                for (int nj = 0; nj < 8; ++nj) {
                    size_t idx = (size_t)(nj >> 1) * N * 32 + (size_t)gr * 32
                               + (nj & 1) * 16 + lrow;
                    h[idx] = __float2half(acc[mi][nj][r] * sc);
                }
            }
        }
    }
}

// ------ aggregation (chunked): relu(dinv[i]*(sum h'[s] + h'[i]) + bias) ------
// chunk = (blockIdx&7)>>1  -> XCD-pinned: each XCD's L2 sees one 3.2MB chunk.
// 4 lanes/node x uint4 (8 halves): 64 nodes per 256-thr block; unroll 8.
__device__ __forceinline__ void acc_row(uint4 u, float* a) {
    float2 q;
    q = __half22float2(*(const __half2*)&u.x); a[0] += q.x; a[1] += q.y;
    q = __half22float2(*(const __half2*)&u.y); a[2] += q.x; a[3] += q.y;
    q = __half22float2(*(const __half2*)&u.z); a[4] += q.x; a[5] += q.y;
    q = __half22float2(*(const __half2*)&u.w); a[6] += q.x; a[7] += q.y;
}

template<int WRITE_F32>
__global__ __launch_bounds__(256) void k_agg(const __half* __restrict__ h,
        const int* __restrict__ row_start, const unsigned short* __restrict__ deg,
        const int* __restrict__ esrc, const float* __restrict__ dinv,
        const float* __restrict__ bias, float* __restrict__ out,
        __half* __restrict__ act, int N) {
    int xcd   = blockIdx.x & 7;
    int chunk = xcd >> 1;
    int rank  = ((blockIdx.x >> 3) << 1) + (xcd & 1);   // 0..2K-1 within chunk
    int node = rank * 64 + (threadIdx.x >> 2);
    int l4 = threadIdx.x & 3;
    if (node >= N) return;
    float di = dinv[node];
    const uint4* hv = (const uint4*)(h + (size_t)chunk * N * 32);  // 4 uint4 per node-row
    int j0 = row_start[node];
    int j1 = j0 + deg[node];

    float a[8] = {};
    acc_row(hv[(size_t)node * 4 + l4], a);   // self-loop h'[node]

    int j = j0;
    for (; j + 8 <= j1; j += 8) {
        int s0 = esrc[j],     s1 = esrc[j + 1], s2 = esrc[j + 2], s3 = esrc[j + 3];
        int s4 = esrc[j + 4], s5 = esrc[j + 5], s6 = esrc[j + 6], s7 = esrc[j + 7];
        uint4 u0 = hv[(size_t)s0 * 4 + l4];
        uint4 u1 = hv[(size_t)s1 * 4 + l4];
        uint4 u2 = hv[(size_t)s2 * 4 + l4];
        uint4 u3 = hv[(size_t)s3 * 4 + l4];
        uint4 u4 = hv[(size_t)s4 * 4 + l4];
        uint4 u5 = hv[(size_t)s5 * 4 + l4];
        uint4 u6 = hv[(size_t)s6 * 4 + l4];
        uint4 u7 = hv[(size_t)s7 * 4 + l4];
        acc_row(u0, a); acc_row(u1, a); acc_row(u2, a); acc_row(u3, a);
        acc_row(u4, a); acc_row(u5, a); acc_row(u6, a); acc_row(u7, a);
    }
    for (; j + 4 <= j1; j += 4) {
        int s0 = esrc[j], s1 = esrc[j + 1], s2 = esrc[j + 2], s3 = esrc[j + 3];
        uint4 u0 = hv[(size_t)s0 * 4 + l4];
        uint4 u1 = hv[(size_t)s1 * 4 + l4];
        uint4 u2 = hv[(size_t)s2 * 4 + l4];
        uint4 u3 = hv[(size_t)s3 * 4 + l4];
        acc_row(u0, a); acc_row(u1, a); acc_row(u2, a); acc_row(u3, a);
    }
    for (; j < j1; ++j) {
        acc_row(hv[(size_t)esrc[j] * 4 + l4], a);
    }
    const float4* b4 = (const float4*)bias;
    float4 bv0 = b4[chunk * 8 + l4 * 2], bv1 = b4[chunk * 8 + l4 * 2 + 1];
    float o[8];
    o[0] = fmaxf(fmaf(a[0], di, bv0.x), 0.f);
    o[1] = fmaxf(fmaf(a[1], di, bv0.y), 0.f);
    o[2] = fmaxf(fmaf(a[2], di, bv0.z), 0.f);
    o[3] = fmaxf(fmaf(a[3], di, bv0.w), 0.f);
    o[4] = fmaxf(fmaf(a[4], di, bv1.x), 0.f);
    o[5] = fmaxf(fmaf(a[5], di, bv1.y), 0.f);
    o[6] = fmaxf(fmaf(a[6], di, bv1.z), 0.f);
    o[7] = fmaxf(fmaf(a[7], di, bv1.w), 0.f);
    if (WRITE_F32) {
        float4* o4 = (float4*)out;   // row-major final output, 32-col slice
        o4[(size_t)node * 32 + chunk * 8 + l4 * 2]     = make_float4(o[0], o[1], o[2], o[3]);
        o4[(size_t)node * 32 + chunk * 8 + l4 * 2 + 1] = make_float4(o[4], o[5], o[6], o[7]);
    } else {
        union { __half2 h2[4]; uint4 u; } pk;
        pk.h2[0] = __floats2half2_rn(o[0], o[1]);
        pk.h2[1] = __floats2half2_rn(o[2], o[3]);
        pk.h2[2] = __floats2half2_rn(o[4], o[5]);
        pk.h2[3] = __floats2half2_rn(o[6], o[7]);
        ((uint4*)act)[(size_t)chunk * N * 4 + (size_t)node * 4 + l4] = pk.u;  // chunked act
    }
}

// ---------------- host launch ----------------
extern "C" void kernel_launch(void* const* d_in, const int* in_sizes, int n_in,
                              void* d_out, int out_size, void* d_ws, size_t ws_size,
                              hipStream_t stream) {
    const float* x  = (const float*)d_in[0];
    const void*  ei = d_in[1];
    const float* W0 = (const float*)d_in[2];
    const float* b0 = (const float*)d_in[3];
    const float* W1 = (const float*)d_in[4];
    const float* b1 = (const float*)d_in[5];
    const float* W2 = (const float*)d_in[6];
    const float* b2 = (const float*)d_in[7];
    float* out = (float*)d_out;

    const int N = in_sizes[0] / D;       // 50000
    const int E = in_sizes[1] / 2;       // 800000

    char* ws = (char*)d_ws;
    size_t off = 0;
    auto alloc = [&](size_t bytes) {
        char* p = ws + off;
        off = (off + bytes + 255) & ~(size_t)255;
        return p;
    };
    int*            flag      = (int*)alloc(4);
    int*            bcur      = (int*)alloc(256 * 4);
    int*            row_start = (int*)alloc((size_t)N * 4);
    unsigned short* deg       = (unsigned short*)alloc((size_t)N * 2);
    float*          dinv      = (float*)alloc((size_t)N * 4);
    int*            esrc      = (int*)alloc((size_t)256 * CAP * 4);
    __half*         hbuf      = (__half*)alloc((size_t)N * D * 2);   // chunked [4][N][32]
    __half*         act       = (__half*)alloc((size_t)N * D * 2);   // chunked [4][N][32]
    __half*         Wt        = (__half*)alloc((size_t)3 * D * D * 2);
    // ebuck (196*CAP*8B = 9.6MB) aliases hbuf (12.8MB): graph build completes
    // before the first GEMM writes hbuf, stream-ordered.
    int2*           ebuck     = (int2*)hbuf;
    (void)ws_size;

    const int nbuck = (N + 255) >> 8;        // 196
    const int nbin  = (E + BIN_CH - 1) / BIN_CH;

    // init (detect + bcur bases + W prep) -> binning -> bucket build
    k_init<<<49, 256, 0, stream>>>((const int*)ei, W0, W1, W2, flag, bcur, Wt);
    k_binning<<<nbin, 256, 0, stream>>>(ei, E, flag, bcur, ebuck);
    k_bucket_build<<<nbuck, 256, 0, stream>>>(ebuck, bcur, row_start, deg, dinv, esrc, N);

    const int gemm_grid = (N + 127) / 128;           // 391
    const int ranks     = (N + 63) / 64;             // 782 (64 nodes/block)
    const int aggB      = (((ranks + 1) / 2)) * 8;   // 8 XCD groups x K

    // layer 0: x(f32) -> hbuf -> act(fp16)
    k_gemm_mfma<false><<<gemm_grid, 256, 0, stream>>>(x, Wt, dinv, hbuf, N);
    k_agg<0><<<aggB, 256, 0, stream>>>(hbuf, row_start, deg, esrc, dinv, b0, out, act, N);
    // layer 1: act -> hbuf -> act
    k_gemm_mfma<true><<<gemm_grid, 256, 0, stream>>>(act, Wt + (size_t)D * D, dinv, hbuf, N);
    k_agg<0><<<aggB, 256, 0, stream>>>(hbuf, row_start, deg, esrc, dinv, b1, out, act, N);
    // layer 2: act -> hbuf -> out(f32)
    k_gemm_mfma<true><<<gemm_grid, 256, 0, stream>>>(act, Wt + (size_t)2 * D * D, dinv, hbuf, N);
    k_agg<1><<<aggB, 256, 0, stream>>>(hbuf, row_start, deg, esrc, dinv, b2, out, act, N);
}